// Round 1
// 368.181 us; speedup vs baseline: 1.1784x; 1.1784x over previous
//
#include <hip/hip_runtime.h>

// SwinAttention1D fused: B=8, C=256, N=16384, W=16, H=4, hd=64.
// One block = 2 windows (32 tokens), 512 threads (8 waves), 2 blocks/CU.
// R1: XOR bank-swizzle on token-major buffers, A-fragment hoisting in P2/P4,
//     weight prefetch across barriers, contiguous repacked weight layout.

#define C_DIM 256
#define NSEQ  16384

typedef __attribute__((ext_vector_type(8))) short bf16x8;
typedef __attribute__((ext_vector_type(4))) float f32x4;

__device__ __forceinline__ unsigned short f2bf(float f) {
    unsigned int u = __builtin_bit_cast(unsigned int, f);
    u += 0x7FFFu + ((u >> 16) & 1u);   // RNE
    return (unsigned short)(u >> 16);
}
__device__ __forceinline__ float bf2f(unsigned short h) {
    unsigned int u = ((unsigned int)h) << 16;
    return __builtin_bit_cast(float, u);
}
__device__ __forceinline__ unsigned int pack2(float a, float b) {
    return ((unsigned int)f2bf(b) << 16) | (unsigned int)f2bf(a);
}
// Bank swizzle: flip one 32B block per 8-row stripe. Decollides dRow=8 store
// pairs (stride = 4 mod 32 words) while keeping 16B alignment of b128 reads.
__device__ __forceinline__ int xsw(int row, int col) {
    return col ^ (((row >> 3) & 1) << 4);
}

// Repack weights: dst[nt][k][l15][quad*8+j] = src[nt*16+l15][k*32+quad*8+j]
// -> each wave's (nt,k) load batch is one contiguous 1KiB block.
__global__ void prep_weights(const float* __restrict__ wq_f, const float* __restrict__ wo_f,
                             unsigned short* __restrict__ wq, unsigned short* __restrict__ wo) {
    int i = blockIdx.x * 256 + threadIdx.x;
    if (i < 768 * 256) {
        int nt = i >> 12, r = i & 4095;
        int k = r >> 9, r2 = r & 511;
        int l = r2 >> 5, r3 = r2 & 31;
        wq[i] = f2bf(wq_f[(nt * 16 + l) * 256 + k * 32 + r3]);
    }
    if (i < 256 * 256) {
        int nt = i >> 12, r = i & 4095;
        int k = r >> 9, r2 = r & 511;
        int l = r2 >> 5, r3 = r2 & 31;
        wo[i] = f2bf(wo_f[(nt * 16 + l) * 256 + k * 32 + r3]);
    }
}

__global__ __launch_bounds__(512, 4) void swin_fused(
    const float* __restrict__ x,
    const unsigned short* __restrict__ wq,   // bf16, repacked [48][8][16][32]
    const unsigned short* __restrict__ wo,   // bf16, repacked [16][8][16][32]
    const float* __restrict__ bq,
    const float* __restrict__ bo,
    const float* __restrict__ lng,
    const float* __restrict__ lnb,
    float* __restrict__ out)
{
    // token-major x tile, rows 16B-aligned (264*2 = 33*16), swizzled cols
    __shared__ __align__(16) unsigned short lds_x[32][264];
    // cols 0-255: q (overwritten by attn in P3), 256-511: k. swizzled cols
    __shared__ __align__(16) unsigned short lds_qk[32][520];
    // v transposed [channel][token], stride 40*2 = 5*16; reused as y (32x264) in P4+
    __shared__ __align__(16) unsigned short lds_vt[256][40];
    __shared__ __align__(16) unsigned short lds_p[8][16][16];
    __shared__ float lds_mean[32];
    __shared__ float lds_rstd[32];

    const int tid  = threadIdx.x;
    const int wv   = tid >> 6;        // 0..7
    const int lane = tid & 63;
    const int l15  = lane & 15;
    const int quad = lane >> 4;

    const int w0    = blockIdx.x * 2;
    const int batch = w0 >> 10;
    const int nbase = (w0 & 1023) << 4;
    const long xbase = (long)batch * ((long)C_DIM * NSEQ) + nbase;

    // ---------- Phase 1: x tile (32 tok x 256 ch) -> LDS bf16, vectorized ----------
    {
        const int t4 = (tid & 7) << 2;           // 4 tokens
        const int c4 = (tid >> 3) << 2;          // 4 channels
        float4 r[4];
        #pragma unroll
        for (int j = 0; j < 4; ++j)
            r[j] = *reinterpret_cast<const float4*>(&x[xbase + (long)(c4 + j) * NSEQ + t4]);
        const float* rf = reinterpret_cast<const float*>(r);
        #pragma unroll
        for (int i = 0; i < 4; ++i) {
            uint2 v;
            v.x = pack2(rf[0 * 4 + i], rf[1 * 4 + i]);
            v.y = pack2(rf[2 * 4 + i], rf[3 * 4 + i]);
            *reinterpret_cast<uint2*>(&lds_x[t4 + i][xsw(t4 + i, c4)]) = v;
        }
    }

    // prefetch P2 i=0 weight fragments (no LDS dependency -> overlaps barrier)
    const unsigned short* wqbase = wq + l15 * 32 + quad * 8;
    bf16x8 bfr[8];
    #pragma unroll
    for (int k = 0; k < 8; ++k)
        bfr[k] = *reinterpret_cast<const bf16x8*>(wqbase + wv * 4096 + k * 512);

    __syncthreads();

    // hoist A-fragments: invariant across all 6 P2 iterations (was 96 reads, now 16)
    bf16x8 xa0[8], xa1[8];
    #pragma unroll
    for (int k = 0; k < 8; ++k) {
        xa0[k] = *reinterpret_cast<const bf16x8*>(&lds_x[l15][xsw(l15, k * 32 + quad * 8)]);
        xa1[k] = *reinterpret_cast<const bf16x8*>(&lds_x[16 + l15][xsw(16 + l15, k * 32 + quad * 8)]);
    }

    // ---------- Phase 2: QKV = x @ Wqkv^T + b (48 N-tiles / 8 waves) ----------
    for (int i = 0; i < 6; ++i) {
        const int nt = (i << 3) + wv;            // 0..47
        const int d  = nt * 16 + l15;            // 0..767
        if (i) {
            #pragma unroll
            for (int k = 0; k < 8; ++k)
                bfr[k] = *reinterpret_cast<const bf16x8*>(wqbase + nt * 4096 + k * 512);
        }
        const float bias = bq[d];
        f32x4 acc0 = {bias, bias, bias, bias};
        f32x4 acc1 = {bias, bias, bias, bias};
        #pragma unroll
        for (int k = 0; k < 8; ++k) {
            acc0 = __builtin_amdgcn_mfma_f32_16x16x32_bf16(xa0[k], bfr[k], acc0, 0, 0, 0);
            acc1 = __builtin_amdgcn_mfma_f32_16x16x32_bf16(xa1[k], bfr[k], acc1, 0, 0, 0);
        }
        if (d < 512) {                            // q | k (wave-uniform branch)
            #pragma unroll
            for (int r = 0; r < 4; ++r) {
                const int r0 = quad * 4 + r;
                lds_qk[r0][xsw(r0, d)]           = f2bf(acc0[r]);
                lds_qk[16 + r0][xsw(16 + r0, d)] = f2bf(acc1[r]);
            }
        } else {                                  // v transposed (unswizzled, minor traffic)
            #pragma unroll
            for (int r = 0; r < 4; ++r) {
                lds_vt[d - 512][quad * 4 + r]      = f2bf(acc0[r]);
                lds_vt[d - 512][16 + quad * 4 + r] = f2bf(acc1[r]);
            }
        }
    }
    __syncthreads();

    // ---------- Phase 3: attention, one (window, head) per wave, no barriers ----------
    {
        const int g = wv >> 2;                   // window in block
        const int h = wv & 3;                    // head
        f32x4 sc = {0.f, 0.f, 0.f, 0.f};
        #pragma unroll
        for (int kk = 0; kk < 2; ++kk) {
            const int row = g * 16 + l15;
            bf16x8 aq = *reinterpret_cast<const bf16x8*>(&lds_qk[row][xsw(row, h * 64 + kk * 32 + quad * 8)]);
            bf16x8 bk = *reinterpret_cast<const bf16x8*>(&lds_qk[row][xsw(row, 256 + h * 64 + kk * 32 + quad * 8)]);
            sc = __builtin_amdgcn_mfma_f32_16x16x32_bf16(aq, bk, sc, 0, 0, 0);
        }
        #pragma unroll
        for (int r = 0; r < 4; ++r) {
            float s = sc[r] * 0.125f;            // 1/sqrt(hd)
            float m = s;
            #pragma unroll
            for (int msk = 1; msk <= 8; msk <<= 1) m = fmaxf(m, __shfl_xor(m, msk, 16));
            float e = __expf(s - m);
            float su = e;
            #pragma unroll
            for (int msk = 1; msk <= 8; msk <<= 1) su += __shfl_xor(su, msk, 16);
            lds_p[wv][quad * 4 + r][l15] = f2bf(e / su);
        }
        // P @ v : K=16 padded to 32 (quads 2,3 zeroed on BOTH operands)
        bf16x8 ap = {0,0,0,0,0,0,0,0};
        if (quad < 2) ap = *reinterpret_cast<const bf16x8*>(&lds_p[wv][l15][quad * 8]);
        #pragma unroll
        for (int dt = 0; dt < 4; ++dt) {
            bf16x8 bv = {0,0,0,0,0,0,0,0};
            if (quad < 2)
                bv = *reinterpret_cast<const bf16x8*>(&lds_vt[h * 64 + dt * 16 + l15][g * 16 + quad * 8]);
            f32x4 acc = {0.f, 0.f, 0.f, 0.f};
            acc = __builtin_amdgcn_mfma_f32_16x16x32_bf16(ap, bv, acc, 0, 0, 0);
            #pragma unroll
            for (int r = 0; r < 4; ++r) {        // overlay attn onto this wave's own q rect
                const int row = g * 16 + quad * 4 + r;
                lds_qk[row][xsw(row, h * 64 + dt * 16 + l15)] = f2bf(acc[r]);
            }
        }
    }

    // prefetch P4 i=0 weight fragments across the barrier
    const unsigned short* wobase = wo + l15 * 32 + quad * 8;
    bf16x8 wfr[8];
    #pragma unroll
    for (int k = 0; k < 8; ++k)
        wfr[k] = *reinterpret_cast<const bf16x8*>(wobase + wv * 4096 + k * 512);

    __syncthreads();

    // ---------- Phase 4: out = attn @ Wo^T + b_o; y = out + x (bf16, overlaid on vt) ----------
    unsigned short* ldy = &lds_vt[0][0];         // 32 x 264 = 8448 <= 10240 shorts
    bf16x8 aa0[8], aa1[8];
    #pragma unroll
    for (int k = 0; k < 8; ++k) {
        aa0[k] = *reinterpret_cast<const bf16x8*>(&lds_qk[l15][xsw(l15, k * 32 + quad * 8)]);
        aa1[k] = *reinterpret_cast<const bf16x8*>(&lds_qk[16 + l15][xsw(16 + l15, k * 32 + quad * 8)]);
    }
    for (int i = 0; i < 2; ++i) {
        const int nt = (i << 3) + wv;            // 0..15
        const int d  = nt * 16 + l15;            // 0..255
        if (i) {
            #pragma unroll
            for (int k = 0; k < 8; ++k)
                wfr[k] = *reinterpret_cast<const bf16x8*>(wobase + nt * 4096 + k * 512);
        }
        const float bias = bo[d];
        f32x4 acc0 = {bias, bias, bias, bias};
        f32x4 acc1 = {bias, bias, bias, bias};
        #pragma unroll
        for (int k = 0; k < 8; ++k) {
            acc0 = __builtin_amdgcn_mfma_f32_16x16x32_bf16(aa0[k], wfr[k], acc0, 0, 0, 0);
            acc1 = __builtin_amdgcn_mfma_f32_16x16x32_bf16(aa1[k], wfr[k], acc1, 0, 0, 0);
        }
        #pragma unroll
        for (int r = 0; r < 4; ++r) {
            const int r0 = quad * 4 + r;
            ldy[r0 * 264 + xsw(r0, d)] =
                f2bf(acc0[r] + bf2f(lds_x[r0][xsw(r0, d)]));
            ldy[(16 + r0) * 264 + xsw(16 + r0, d)] =
                f2bf(acc1[r] + bf2f(lds_x[16 + r0][xsw(16 + r0, d)]));
        }
    }
    __syncthreads();

    // ---------- Phase 5a: LN stats (16 threads per token row, b128 reads) ----------
    {
        const int row = tid >> 4, part = tid & 15;
        float s = 0.f, sq = 0.f;
        #pragma unroll
        for (int half = 0; half < 2; ++half) {
            bf16x8 yv = *reinterpret_cast<const bf16x8*>(&ldy[row * 264 + xsw(row, part * 16 + half * 8)]);
            #pragma unroll
            for (int ii = 0; ii < 8; ++ii) {
                float v = bf2f((unsigned short)yv[ii]);
                s += v; sq += v * v;
            }
        }
        #pragma unroll
        for (int msk = 1; msk <= 8; msk <<= 1) {
            s  += __shfl_xor(s,  msk, 16);
            sq += __shfl_xor(sq, msk, 16);
        }
        if (part == 0) {
            float mean = s * (1.0f / 256.0f);
            float var  = sq * (1.0f / 256.0f) - mean * mean;
            lds_mean[row] = mean;
            lds_rstd[row] = rsqrtf(var + 1e-5f);
        }
    }
    __syncthreads();

    // ---------- Phase 5b: normalize + vectorized transposed store ----------
    {
        const int t4 = (tid & 7) << 2;
        const int c0 = tid >> 3;                 // 0..63
        float mean[4], rstd[4];
        #pragma unroll
        for (int i = 0; i < 4; ++i) { mean[i] = lds_mean[t4 + i]; rstd[i] = lds_rstd[t4 + i]; }
        #pragma unroll
        for (int it = 0; it < 4; ++it) {
            const int c = c0 + (it << 6);
            const float g = lng[c], b = lnb[c];
            float4 o;
            float* of = reinterpret_cast<float*>(&o);
            #pragma unroll
            for (int i = 0; i < 4; ++i)
                of[i] = (bf2f(ldy[(t4 + i) * 264 + xsw(t4 + i, c)]) - mean[i]) * rstd[i] * g + b;
            *reinterpret_cast<float4*>(&out[xbase + (long)c * NSEQ + t4]) = o;
        }
    }
}

extern "C" void kernel_launch(void* const* d_in, const int* in_sizes, int n_in,
                              void* d_out, int out_size, void* d_ws, size_t ws_size,
                              hipStream_t stream) {
    const float* x   = (const float*)d_in[0];
    const float* ipw = (const float*)d_in[1];
    const float* ipb = (const float*)d_in[2];
    const float* opw = (const float*)d_in[3];
    const float* opb = (const float*)d_in[4];
    const float* lng = (const float*)d_in[5];
    const float* lnb = (const float*)d_in[6];
    float* out = (float*)d_out;

    unsigned short* wq = (unsigned short*)d_ws;
    unsigned short* wo = wq + 768 * 256;

    prep_weights<<<768, 256, 0, stream>>>(ipw, opw, wq, wo);
    swin_fused<<<4096, 512, 0, stream>>>(x, wq, wo, ipb, opb, lng, lnb, out);
}

// Round 2
// 350.178 us; speedup vs baseline: 1.2390x; 1.0514x over previous
//
#include <hip/hip_runtime.h>

// SwinAttention1D fused: B=8, C=256, N=16384, W=16, H=4, hd=64.
// One block = 2 windows (32 tokens), 512 threads (8 waves), 2 blocks/CU.
// R2: operand-swapped MFMAs so C-fragments come out row=d/col=token ->
//     all QKV / attn / y / residual LDS traffic becomes packed b64 ops
//     (scalar ds_*_b16 count ~116 -> ~24 per thread).

#define C_DIM 256
#define NSEQ  16384

typedef __attribute__((ext_vector_type(8))) short bf16x8;
typedef __attribute__((ext_vector_type(4))) float f32x4;

__device__ __forceinline__ unsigned short f2bf(float f) {
    unsigned int u = __builtin_bit_cast(unsigned int, f);
    u += 0x7FFFu + ((u >> 16) & 1u);   // RNE
    return (unsigned short)(u >> 16);
}
__device__ __forceinline__ float bf2f(unsigned short h) {
    unsigned int u = ((unsigned int)h) << 16;
    return __builtin_bit_cast(float, u);
}
__device__ __forceinline__ unsigned int pack2(float a, float b) {
    return ((unsigned int)f2bf(b) << 16) | (unsigned int)f2bf(a);
}
__device__ __forceinline__ uint2 pack4(f32x4 v) {
    uint2 r; r.x = pack2(v[0], v[1]); r.y = pack2(v[2], v[3]); return r;
}
// Bank swizzle: flip one 32B block per 8-row stripe. All vector accesses use
// bases that keep the access inside one 16-col granule, so XOR of bit 4 is a
// consistent element-wise permutation.
__device__ __forceinline__ int xsw(int row, int col) {
    return col ^ (((row >> 3) & 1) << 4);
}

// Repack weights: dst[nt][k][l15][quad*8+j] = src[nt*16+l15][k*32+quad*8+j]
__global__ void prep_weights(const float* __restrict__ wq_f, const float* __restrict__ wo_f,
                             unsigned short* __restrict__ wq, unsigned short* __restrict__ wo) {
    int i = blockIdx.x * 256 + threadIdx.x;
    if (i < 768 * 256) {
        int nt = i >> 12, r = i & 4095;
        int k = r >> 9, r2 = r & 511;
        int l = r2 >> 5, r3 = r2 & 31;
        wq[i] = f2bf(wq_f[(nt * 16 + l) * 256 + k * 32 + r3]);
    }
    if (i < 256 * 256) {
        int nt = i >> 12, r = i & 4095;
        int k = r >> 9, r2 = r & 511;
        int l = r2 >> 5, r3 = r2 & 31;
        wo[i] = f2bf(wo_f[(nt * 16 + l) * 256 + k * 32 + r3]);
    }
}

__global__ __launch_bounds__(512, 4) void swin_fused(
    const float* __restrict__ x,
    const unsigned short* __restrict__ wq,   // bf16, repacked [48][8][16][32]
    const unsigned short* __restrict__ wo,   // bf16, repacked [16][8][16][32]
    const float* __restrict__ bq,
    const float* __restrict__ bo,
    const float* __restrict__ lng,
    const float* __restrict__ lnb,
    float* __restrict__ out)
{
    __shared__ __align__(16) unsigned short lds_x[32][264];   // token-major x, swizzled
    __shared__ __align__(16) unsigned short lds_qk[32][520];  // q | k, swizzled; attn overlays q
    __shared__ __align__(16) unsigned short lds_vt[256][40];  // v^T [ch][tok]; reused as y later
    __shared__ __align__(16) unsigned short lds_p[8][16][16];
    __shared__ float lds_mean[32];
    __shared__ float lds_rstd[32];

    const int tid  = threadIdx.x;
    const int wv   = tid >> 6;
    const int lane = tid & 63;
    const int l15  = lane & 15;
    const int quad = lane >> 4;

    const int w0    = blockIdx.x * 2;
    const int batch = w0 >> 10;
    const int nbase = (w0 & 1023) << 4;
    const long xbase = (long)batch * ((long)C_DIM * NSEQ) + nbase;

    // ---------- Phase 1: x tile (32 tok x 256 ch) -> LDS bf16 ----------
    {
        const int t4 = (tid & 7) << 2;
        const int c4 = (tid >> 3) << 2;
        float4 r[4];
        #pragma unroll
        for (int j = 0; j < 4; ++j)
            r[j] = *reinterpret_cast<const float4*>(&x[xbase + (long)(c4 + j) * NSEQ + t4]);
        const float* rf = reinterpret_cast<const float*>(r);
        #pragma unroll
        for (int i = 0; i < 4; ++i) {
            uint2 v;
            v.x = pack2(rf[0 * 4 + i], rf[1 * 4 + i]);
            v.y = pack2(rf[2 * 4 + i], rf[3 * 4 + i]);
            *reinterpret_cast<uint2*>(&lds_x[t4 + i][xsw(t4 + i, c4)]) = v;
        }
    }

    // prefetch P2 i=0 weight fragments (no LDS dependency -> overlaps barrier)
    const unsigned short* wqbase = wq + l15 * 32 + quad * 8;
    bf16x8 bfr[8];
    #pragma unroll
    for (int k = 0; k < 8; ++k)
        bfr[k] = *reinterpret_cast<const bf16x8*>(wqbase + wv * 4096 + k * 512);

    __syncthreads();

    // x fragments (lane = token row, 8 contiguous channels per frag)
    bf16x8 xa0[8], xa1[8];
    #pragma unroll
    for (int k = 0; k < 8; ++k) {
        xa0[k] = *reinterpret_cast<const bf16x8*>(&lds_x[l15][xsw(l15, k * 32 + quad * 8)]);
        xa1[k] = *reinterpret_cast<const bf16x8*>(&lds_x[16 + l15][xsw(16 + l15, k * 32 + quad * 8)]);
    }

    // ---------- Phase 2a: q,k tiles (nt 0..31), SWAPPED: C = W . x^T ----------
    // lane holds (token=l15, d = nt*16+quad*4+r) -> packed b64 stores, token-major
    for (int i = 0; i < 4; ++i) {
        const int nt = (i << 3) + wv;            // 0..31
        if (i) {
            #pragma unroll
            for (int k = 0; k < 8; ++k)
                bfr[k] = *reinterpret_cast<const bf16x8*>(wqbase + nt * 4096 + k * 512);
        }
        const float4 b4 = *reinterpret_cast<const float4*>(&bq[nt * 16 + quad * 4]);
        f32x4 acc0 = {b4.x, b4.y, b4.z, b4.w};
        f32x4 acc1 = acc0;
        #pragma unroll
        for (int k = 0; k < 8; ++k) {
            acc0 = __builtin_amdgcn_mfma_f32_16x16x32_bf16(bfr[k], xa0[k], acc0, 0, 0, 0);
            acc1 = __builtin_amdgcn_mfma_f32_16x16x32_bf16(bfr[k], xa1[k], acc1, 0, 0, 0);
        }
        const int cb = nt * 16 + quad * 4;
        *reinterpret_cast<uint2*>(&lds_qk[l15][xsw(l15, cb)])           = pack4(acc0);
        *reinterpret_cast<uint2*>(&lds_qk[16 + l15][xsw(16 + l15, cb)]) = pack4(acc1);
    }
    // ---------- Phase 2b: v tiles (nt 32..47), original order: C = x . W^T ----------
    // lane holds (d = nt*16+l15, tokens quad*4..+3) -> packed b64 stores into v^T
    for (int i = 4; i < 6; ++i) {
        const int nt = (i << 3) + wv;            // 32..47
        #pragma unroll
        for (int k = 0; k < 8; ++k)
            bfr[k] = *reinterpret_cast<const bf16x8*>(wqbase + nt * 4096 + k * 512);
        const int d = nt * 16 + l15;             // 512..767
        const float bias = bq[d];
        f32x4 acc0 = {bias, bias, bias, bias};
        f32x4 acc1 = acc0;
        #pragma unroll
        for (int k = 0; k < 8; ++k) {
            acc0 = __builtin_amdgcn_mfma_f32_16x16x32_bf16(xa0[k], bfr[k], acc0, 0, 0, 0);
            acc1 = __builtin_amdgcn_mfma_f32_16x16x32_bf16(xa1[k], bfr[k], acc1, 0, 0, 0);
        }
        *reinterpret_cast<uint2*>(&lds_vt[d - 512][quad * 4])      = pack4(acc0);
        *reinterpret_cast<uint2*>(&lds_vt[d - 512][16 + quad * 4]) = pack4(acc1);
    }
    __syncthreads();

    // ---------- Phase 3: attention, one (window, head) per wave ----------
    {
        const int g = wv >> 2;
        const int h = wv & 3;
        f32x4 sc = {0.f, 0.f, 0.f, 0.f};
        #pragma unroll
        for (int kk = 0; kk < 2; ++kk) {
            const int row = g * 16 + l15;
            bf16x8 aq = *reinterpret_cast<const bf16x8*>(&lds_qk[row][xsw(row, h * 64 + kk * 32 + quad * 8)]);
            bf16x8 bk = *reinterpret_cast<const bf16x8*>(&lds_qk[row][xsw(row, 256 + h * 64 + kk * 32 + quad * 8)]);
            sc = __builtin_amdgcn_mfma_f32_16x16x32_bf16(aq, bk, sc, 0, 0, 0);
        }
        #pragma unroll
        for (int r = 0; r < 4; ++r) {
            float s = sc[r] * 0.125f;            // 1/sqrt(hd)
            float m = s;
            #pragma unroll
            for (int msk = 1; msk <= 8; msk <<= 1) m = fmaxf(m, __shfl_xor(m, msk, 16));
            float e = __expf(s - m);
            float su = e;
            #pragma unroll
            for (int msk = 1; msk <= 8; msk <<= 1) su += __shfl_xor(su, msk, 16);
            lds_p[wv][quad * 4 + r][l15] = f2bf(e / su);
        }
        // P @ v, SWAPPED: C = V^T . P^T -> lane holds (token=l15, 4 consecutive d)
        bf16x8 ap = {0,0,0,0,0,0,0,0};
        if (quad < 2) ap = *reinterpret_cast<const bf16x8*>(&lds_p[wv][l15][quad * 8]);
        #pragma unroll
        for (int dt = 0; dt < 4; ++dt) {
            bf16x8 bv = {0,0,0,0,0,0,0,0};
            if (quad < 2)
                bv = *reinterpret_cast<const bf16x8*>(&lds_vt[h * 64 + dt * 16 + l15][g * 16 + quad * 8]);
            f32x4 acc = {0.f, 0.f, 0.f, 0.f};
            acc = __builtin_amdgcn_mfma_f32_16x16x32_bf16(bv, ap, acc, 0, 0, 0);
            const int row = g * 16 + l15;
            const int cb  = h * 64 + dt * 16 + quad * 4;
            *reinterpret_cast<uint2*>(&lds_qk[row][xsw(row, cb)]) = pack4(acc);
        }
    }

    // prefetch P4 i=0 weight fragments across the barrier
    const unsigned short* wobase = wo + l15 * 32 + quad * 8;
    bf16x8 wfr[8];
    #pragma unroll
    for (int k = 0; k < 8; ++k)
        wfr[k] = *reinterpret_cast<const bf16x8*>(wobase + wv * 4096 + k * 512);

    __syncthreads();

    // ---------- Phase 4: out = attn @ Wo^T + b_o (SWAPPED); y = out + x ----------
    unsigned short* ldy = &lds_vt[0][0];         // 32 x 264 token-major, swizzled
    bf16x8 aa0[8], aa1[8];
    #pragma unroll
    for (int k = 0; k < 8; ++k) {
        aa0[k] = *reinterpret_cast<const bf16x8*>(&lds_qk[l15][xsw(l15, k * 32 + quad * 8)]);
        aa1[k] = *reinterpret_cast<const bf16x8*>(&lds_qk[16 + l15][xsw(16 + l15, k * 32 + quad * 8)]);
    }
    for (int i = 0; i < 2; ++i) {
        const int nt = (i << 3) + wv;            // 0..15
        if (i) {
            #pragma unroll
            for (int k = 0; k < 8; ++k)
                wfr[k] = *reinterpret_cast<const bf16x8*>(wobase + nt * 4096 + k * 512);
        }
        const float4 b4 = *reinterpret_cast<const float4*>(&bo[nt * 16 + quad * 4]);
        f32x4 acc0 = {b4.x, b4.y, b4.z, b4.w};
        f32x4 acc1 = acc0;
        #pragma unroll
        for (int k = 0; k < 8; ++k) {
            acc0 = __builtin_amdgcn_mfma_f32_16x16x32_bf16(wfr[k], aa0[k], acc0, 0, 0, 0);
            acc1 = __builtin_amdgcn_mfma_f32_16x16x32_bf16(wfr[k], aa1[k], acc1, 0, 0, 0);
        }
        const int cb = nt * 16 + quad * 4;
        {   // tokens 0..15 (col = l15)
            uint2 xr = *reinterpret_cast<const uint2*>(&lds_x[l15][xsw(l15, cb)]);
            f32x4 y;
            y[0] = acc0[0] + bf2f((unsigned short)(xr.x & 0xffff));
            y[1] = acc0[1] + bf2f((unsigned short)(xr.x >> 16));
            y[2] = acc0[2] + bf2f((unsigned short)(xr.y & 0xffff));
            y[3] = acc0[3] + bf2f((unsigned short)(xr.y >> 16));
            *reinterpret_cast<uint2*>(&ldy[l15 * 264 + xsw(l15, cb)]) = pack4(y);
        }
        {   // tokens 16..31
            uint2 xr = *reinterpret_cast<const uint2*>(&lds_x[16 + l15][xsw(16 + l15, cb)]);
            f32x4 y;
            y[0] = acc1[0] + bf2f((unsigned short)(xr.x & 0xffff));
            y[1] = acc1[1] + bf2f((unsigned short)(xr.x >> 16));
            y[2] = acc1[2] + bf2f((unsigned short)(xr.y & 0xffff));
            y[3] = acc1[3] + bf2f((unsigned short)(xr.y >> 16));
            *reinterpret_cast<uint2*>(&ldy[(16 + l15) * 264 + xsw(16 + l15, cb)]) = pack4(y);
        }
    }
    __syncthreads();

    // ---------- Phase 5a: LN stats (16 threads per token row, b128 reads) ----------
    {
        const int row = tid >> 4, part = tid & 15;
        float s = 0.f, sq = 0.f;
        #pragma unroll
        for (int half = 0; half < 2; ++half) {
            bf16x8 yv = *reinterpret_cast<const bf16x8*>(&ldy[row * 264 + xsw(row, part * 16 + half * 8)]);
            #pragma unroll
            for (int ii = 0; ii < 8; ++ii) {
                float v = bf2f((unsigned short)yv[ii]);
                s += v; sq += v * v;
            }
        }
        #pragma unroll
        for (int msk = 1; msk <= 8; msk <<= 1) {
            s  += __shfl_xor(s,  msk, 16);
            sq += __shfl_xor(sq, msk, 16);
        }
        if (part == 0) {
            float mean = s * (1.0f / 256.0f);
            float var  = sq * (1.0f / 256.0f) - mean * mean;
            lds_mean[row] = mean;
            lds_rstd[row] = rsqrtf(var + 1e-5f);
        }
    }
    __syncthreads();

    // ---------- Phase 5b: normalize + vectorized transposed store ----------
    {
        const int t4 = (tid & 7) << 2;
        const int c0 = tid >> 3;
        float mean[4], rstd[4];
        #pragma unroll
        for (int i = 0; i < 4; ++i) { mean[i] = lds_mean[t4 + i]; rstd[i] = lds_rstd[t4 + i]; }
        #pragma unroll
        for (int it = 0; it < 4; ++it) {
            const int c = c0 + (it << 6);
            const float g = lng[c], b = lnb[c];
            float4 o;
            float* of = reinterpret_cast<float*>(&o);
            #pragma unroll
            for (int i = 0; i < 4; ++i)
                of[i] = (bf2f(ldy[(t4 + i) * 264 + xsw(t4 + i, c)]) - mean[i]) * rstd[i] * g + b;
            *reinterpret_cast<float4*>(&out[xbase + (long)c * NSEQ + t4]) = o;
        }
    }
}

extern "C" void kernel_launch(void* const* d_in, const int* in_sizes, int n_in,
                              void* d_out, int out_size, void* d_ws, size_t ws_size,
                              hipStream_t stream) {
    const float* x   = (const float*)d_in[0];
    const float* ipw = (const float*)d_in[1];
    const float* ipb = (const float*)d_in[2];
    const float* opw = (const float*)d_in[3];
    const float* opb = (const float*)d_in[4];
    const float* lng = (const float*)d_in[5];
    const float* lnb = (const float*)d_in[6];
    float* out = (float*)d_out;

    unsigned short* wq = (unsigned short*)d_ws;
    unsigned short* wo = wq + 768 * 256;

    prep_weights<<<768, 256, 0, stream>>>(ipw, opw, wq, wo);
    swin_fused<<<4096, 512, 0, stream>>>(x, wq, wo, ipb, opb, lng, lnb, out);
}